// Round 1
// 6886.167 us; speedup vs baseline: 4.0353x; 4.0353x over previous
//
#include <hip/hip_runtime.h>
#include <math.h>

#define T_TOK 2048
#define HIDDEN 512
#define FFDIM 2048
#define VOCAB 50257

typedef _Float16 h4 __attribute__((ext_vector_type(4)));
typedef float f4 __attribute__((ext_vector_type(4)));

// ---------------- embedding gather (f32 -> f32) ----------------
__global__ __launch_bounds__(256) void gather_rows(const int* __restrict__ tokens,
                                                   const float* __restrict__ embed,
                                                   float* __restrict__ h) {
    int t = blockIdx.x;
    int tok = tokens[t];
    const float2* src = (const float2*)(embed + (size_t)tok * HIDDEN);
    float2* dst = (float2*)(h + (size_t)t * HIDDEN);
    dst[threadIdx.x] = src[threadIdx.x];
}

// ---------------- LayerNorm (one block per row of 512), fp16 out ----------------
__global__ __launch_bounds__(256) void ln_rows_h(const float* __restrict__ x,
                                                 const float* __restrict__ g,
                                                 const float* __restrict__ b,
                                                 _Float16* __restrict__ y) {
    int t = blockIdx.x;
    int tid = threadIdx.x;
    const float* xr = x + (size_t)t * HIDDEN;
    float v0 = xr[tid], v1 = xr[tid + 256];
    float s = v0 + v1;
    float q = v0 * v0 + v1 * v1;
    for (int off = 32; off > 0; off >>= 1) {
        s += __shfl_down(s, off);
        q += __shfl_down(q, off);
    }
    __shared__ float ss[4], qq[4];
    int w = tid >> 6;
    if ((tid & 63) == 0) { ss[w] = s; qq[w] = q; }
    __syncthreads();
    float S = ss[0] + ss[1] + ss[2] + ss[3];
    float Q = qq[0] + qq[1] + qq[2] + qq[3];
    float mu = S * (1.0f / HIDDEN);
    float var = Q * (1.0f / HIDDEN) - mu * mu;
    float r = rsqrtf(var + 1e-5f);
    _Float16* yr = y + (size_t)t * HIDDEN;
    yr[tid]       = (_Float16)((v0 - mu) * r * g[tid]       + b[tid]);
    yr[tid + 256] = (_Float16)((v1 - mu) * r * g[tid + 256] + b[tid + 256]);
}

// ---------------- transpose+cast: in f32[R][C] -> out fp16[C][R] ----------------
__global__ __launch_bounds__(256) void transpose_cast(const float* __restrict__ in,
                                                      _Float16* __restrict__ out,
                                                      int R, int C) {
    __shared__ float t[64][65];
    int r0 = blockIdx.y * 64, c0 = blockIdx.x * 64;
    int tid = threadIdx.x;
    for (int i = tid; i < 64 * 64; i += 256) {
        int r = i >> 6, c = i & 63;
        t[r][c] = in[(size_t)(r0 + r) * C + c0 + c];
    }
    __syncthreads();
    for (int i = tid; i < 64 * 64; i += 256) {
        int r = i >> 6, c = i & 63;
        out[(size_t)(c0 + r) * R + r0 + c] = (_Float16)t[c][r];
    }
}

// ---------------- MFMA fp16 GEMM: C[M,N] = A[M,K] x Bt[N,K]^T ----------------
// A fp16 row-major. Bt row-major [N,K] (i.e. B transposed); BF32=1 -> Bt is f32,
// converted to fp16 during LDS staging. fp32 accumulate. 256 thr = 4 waves (2x2),
// each wave owns (BM/2)x(BN/2) via 16x16x16 MFMA frags. Double-buffered LDS with
// reg-staging: global loads for tile k+1 issued before the barrier, MFMAs hide them.
template <int BM, int BN, int BK, int ACT, int HASBIAS, int OUT16, int BF32>
__global__ __launch_bounds__(256) void gemm_mfma(const _Float16* __restrict__ A,
                                                 const void* __restrict__ Bv,
                                                 const float* __restrict__ bias,
                                                 void* __restrict__ Cv,
                                                 int M, int N, int K) {
    constexpr int SPR = BK / 8;              // 16B (8-half) segments per LDS row
    constexpr int PA  = BM * SPR / 256;      // staging passes for A
    constexpr int PB  = BN * SPR / 256;      // staging passes for B
    constexpr int FM  = BM / 32;             // 16x16 frags per wave (M)
    constexpr int FN  = BN / 32;             // 16x16 frags per wave (N)
    static_assert(PA * 256 == BM * SPR && PB * 256 == BN * SPR, "staging");

    __shared__ _Float16 As[2][BM][BK + 4];   // +4 halves pad: conflict-free ds_read_b64
    __shared__ _Float16 Bs[2][BN][BK + 4];

    const int tid  = threadIdx.x;
    const int m0   = blockIdx.y * BM, n0 = blockIdx.x * BN;
    const int lane = tid & 63;
    const int w    = tid >> 6;
    const int wm   = (w >> 1) * (BM / 2);
    const int wn   = (w & 1) * (BN / 2);
    const int mlane = lane & 15;
    const int klane = (lane >> 4) * 4;

    const f4 fz = {0.f, 0.f, 0.f, 0.f};
    f4 acc[FM][FN];
#pragma unroll
    for (int i = 0; i < FM; ++i)
#pragma unroll
        for (int j = 0; j < FN; ++j) acc[i][j] = fz;

    f4 ra[PA];
    f4 rb[PB * (BF32 ? 2 : 1)];

    auto loadA = [&](int k0) {
#pragma unroll
        for (int p = 0; p < PA; ++p) {
            int idx = p * 256 + tid;
            int r = idx / SPR, s = idx % SPR;
            ra[p] = *(const f4*)(A + (size_t)(m0 + r) * K + k0 + s * 8);
        }
    };
    auto loadB = [&](int k0) {
#pragma unroll
        for (int p = 0; p < PB; ++p) {
            int idx = p * 256 + tid;
            int r = idx / SPR, s = idx % SPR;
            int n = n0 + r;
            if constexpr (BF32) {
                const float* Bf = (const float*)Bv;
                f4 u0 = fz, u1 = fz;
                if (n < N) {
                    u0 = *(const f4*)(Bf + (size_t)n * K + k0 + s * 8);
                    u1 = *(const f4*)(Bf + (size_t)n * K + k0 + s * 8 + 4);
                }
                rb[2 * p] = u0; rb[2 * p + 1] = u1;
            } else {
                const _Float16* Bh = (const _Float16*)Bv;
                f4 u = fz;
                if (n < N) u = *(const f4*)(Bh + (size_t)n * K + k0 + s * 8);
                rb[p] = u;
            }
        }
    };
    auto stage = [&](int buf) {
#pragma unroll
        for (int p = 0; p < PA; ++p) {
            int idx = p * 256 + tid;
            int r = idx / SPR, s = idx % SPR;
            float2 t0; t0.x = ra[p].x; t0.y = ra[p].y;
            float2 t1; t1.x = ra[p].z; t1.y = ra[p].w;
            *(float2*)&As[buf][r][s * 8]     = t0;
            *(float2*)&As[buf][r][s * 8 + 4] = t1;
        }
#pragma unroll
        for (int p = 0; p < PB; ++p) {
            int idx = p * 256 + tid;
            int r = idx / SPR, s = idx % SPR;
            if constexpr (BF32) {
                f4 u0 = rb[2 * p], u1 = rb[2 * p + 1];
                h4 lo = {(_Float16)u0.x, (_Float16)u0.y, (_Float16)u0.z, (_Float16)u0.w};
                h4 hi = {(_Float16)u1.x, (_Float16)u1.y, (_Float16)u1.z, (_Float16)u1.w};
                *(h4*)&Bs[buf][r][s * 8]     = lo;
                *(h4*)&Bs[buf][r][s * 8 + 4] = hi;
            } else {
                float2 t0; t0.x = rb[p].x; t0.y = rb[p].y;
                float2 t1; t1.x = rb[p].z; t1.y = rb[p].w;
                *(float2*)&Bs[buf][r][s * 8]     = t0;
                *(float2*)&Bs[buf][r][s * 8 + 4] = t1;
            }
        }
    };

    loadA(0); loadB(0); stage(0);
    int cur = 0;
    for (int k0 = 0; k0 < K; k0 += BK, cur ^= 1) {
        bool nxt = (k0 + BK) < K;
        if (nxt) { loadA(k0 + BK); loadB(k0 + BK); }
        __syncthreads();
#pragma unroll
        for (int kk = 0; kk < BK / 16; ++kk) {
            const int kb = kk * 16 + klane;
            h4 af[FM], bf[FN];
#pragma unroll
            for (int i = 0; i < FM; ++i)
                af[i] = *(const h4*)&As[cur][wm + i * 16 + mlane][kb];
#pragma unroll
            for (int j = 0; j < FN; ++j)
                bf[j] = *(const h4*)&Bs[cur][wn + j * 16 + mlane][kb];
#pragma unroll
            for (int i = 0; i < FM; ++i)
#pragma unroll
                for (int j = 0; j < FN; ++j)
                    acc[i][j] = __builtin_amdgcn_mfma_f32_16x16x16f16(af[i], bf[j], acc[i][j], 0, 0, 0);
        }
        if (nxt) stage(cur ^ 1);  // writes other buffer; next-iter barrier orders readers
    }

    // epilogue: D frag layout col=lane&15, row=(lane>>4)*4+q
#pragma unroll
    for (int i = 0; i < FM; ++i) {
#pragma unroll
        for (int j = 0; j < FN; ++j) {
            int c = n0 + wn + j * 16 + mlane;
            if (c < N) {
                float bv = HASBIAS ? bias[c] : 0.f;
#pragma unroll
                for (int q = 0; q < 4; ++q) {
                    int r = m0 + wm + i * 16 + klane + q;
                    float v = acc[i][j][q] + bv;
                    if (ACT) v = 0.5f * v * (1.0f + erff(v * 0.70710678118654752f));
                    if (OUT16) ((_Float16*)Cv)[(size_t)r * N + c] = (_Float16)v;
                    else       ((float*)Cv)[(size_t)r * N + c] = v;
                }
            }
        }
    }
}

// ---------------- RK4 stage combine (unchanged, f32) ----------------
__global__ __launch_bounds__(256) void rk4_stage(float* __restrict__ h,
                                                 const float* __restrict__ k,
                                                 float* __restrict__ acc,
                                                 float* __restrict__ tmp,
                                                 float dt, int stage) {
    int i = blockIdx.x * blockDim.x + threadIdx.x;
    float4 kv = ((const float4*)k)[i];
    float4 hv = ((const float4*)h)[i];
    if (stage == 0) {
        ((float4*)acc)[i] = kv;
        float c = 0.5f * dt;
        float4 t = {hv.x + c * kv.x, hv.y + c * kv.y, hv.z + c * kv.z, hv.w + c * kv.w};
        ((float4*)tmp)[i] = t;
    } else if (stage == 1 || stage == 2) {
        float4 av = ((const float4*)acc)[i];
        av.x += 2.f * kv.x; av.y += 2.f * kv.y; av.z += 2.f * kv.z; av.w += 2.f * kv.w;
        ((float4*)acc)[i] = av;
        float c = (stage == 1) ? 0.5f * dt : dt;
        float4 t = {hv.x + c * kv.x, hv.y + c * kv.y, hv.z + c * kv.z, hv.w + c * kv.w};
        ((float4*)tmp)[i] = t;
    } else {
        float4 av = ((const float4*)acc)[i];
        float c = dt * (1.0f / 6.0f);
        hv.x += c * (av.x + kv.x); hv.y += c * (av.y + kv.y);
        hv.z += c * (av.z + kv.z); hv.w += c * (av.w + kv.w);
        ((float4*)h)[i] = hv;
    }
}

extern "C" void kernel_launch(void* const* d_in, const int* in_sizes, int n_in,
                              void* d_out, int out_size, void* d_ws, size_t ws_size,
                              hipStream_t stream) {
    const int*   tokens = (const int*)d_in[0];
    const float* embed  = (const float*)d_in[1];
    const float* ln1_g  = (const float*)d_in[2];
    const float* ln1_b  = (const float*)d_in[3];
    const float* w1     = (const float*)d_in[4];
    const float* b1     = (const float*)d_in[5];
    const float* w2     = (const float*)d_in[6];
    const float* b2     = (const float*)d_in[7];
    const float* nf_g   = (const float*)d_in[8];
    const float* nf_b   = (const float*)d_in[9];
    float* out = (float*)d_out;

    float* ws = (float*)d_ws;
    const size_t NH = (size_t)T_TOK * HIDDEN;      // 1M elements
    float* h    = ws;                               // 4 MB
    float* tmp  = ws + NH;                          // 4 MB
    float* acc  = ws + 2 * NH;                      // 4 MB
    float* kbuf = ws + 3 * NH;                      // 4 MB
    _Float16* yln_h = (_Float16*)(ws + 4 * NH);     // 2 MB (fits in NH floats)
    // ws total: 18 MB  (previous kernel proved ws >= 20 MB)

    // d_out as scratch: w1t/w2t/z_h all dead before the head GEMM writes out.
    char* ob = (char*)d_out;
    _Float16* w1t = (_Float16*)ob;                          // [FFDIM][HIDDEN]  2 MB
    _Float16* w2t = (_Float16*)(ob + (2ull << 20));         // [HIDDEN][FFDIM]  2 MB
    _Float16* z_h = (_Float16*)(ob + (4ull << 20));         // [T_TOK][FFDIM]   8 MB

    // one-time per call: weight transpose+cast (~20 us)
    transpose_cast<<<dim3(FFDIM / 64, HIDDEN / 64), 256, 0, stream>>>(w1, w1t, HIDDEN, FFDIM);
    transpose_cast<<<dim3(HIDDEN / 64, FFDIM / 64), 256, 0, stream>>>(w2, w2t, FFDIM, HIDDEN);

    gather_rows<<<T_TOK, 256, 0, stream>>>(tokens, embed, h);

    // Graded RK4 schedule (unchanged; sums exactly to 1.0).
    const int NSCHED = 34;
    float steps[NSCHED];
    {
        int i = 0;
        for (int j = 0; j < 8; ++j) steps[i++] = 1.0f / 256.0f;
        for (int j = 0; j < 8; ++j) steps[i++] = 1.0f / 64.0f;
        for (int j = 0; j < 8; ++j) steps[i++] = 1.0f / 32.0f;
        for (int j = 0; j < 10; ++j) steps[i++] = 0.059375f;
    }

    const int n4blocks = (T_TOK * HIDDEN / 4) / 256;  // 1024
    for (int step = 0; step < NSCHED; ++step) {
        const float dt = steps[step];
        for (int stage = 0; stage < 4; ++stage) {
            const float* src = (stage == 0) ? h : tmp;
            ln_rows_h<<<T_TOK, 256, 0, stream>>>(src, ln1_g, ln1_b, yln_h);
            // z = GELU(yln @ w1 + b1)   [2048 x 2048], fp16 out
            gemm_mfma<128, 64, 32, 1, 1, 1, 0>
                <<<dim3(FFDIM / 64, T_TOK / 128), 256, 0, stream>>>(
                    yln_h, w1t, b1, z_h, T_TOK, FFDIM, HIDDEN);
            // k = z @ w2 + b2           [2048 x 512], f32 out
            gemm_mfma<64, 64, 64, 0, 1, 0, 0>
                <<<dim3(HIDDEN / 64, T_TOK / 64), 256, 0, stream>>>(
                    z_h, w2t, b2, kbuf, T_TOK, HIDDEN, FFDIM);
            rk4_stage<<<n4blocks, 256, 0, stream>>>(h, kbuf, acc, tmp, dt, stage);
        }
    }

    ln_rows_h<<<T_TOK, 256, 0, stream>>>(h, nf_g, nf_b, yln_h);
    // logits = yln @ embed^T  — embed consumed f32, cast to fp16 in staging
    gemm_mfma<128, 128, 32, 0, 0, 0, 1>
        <<<dim3((VOCAB + 127) / 128, T_TOK / 128), 256, 0, stream>>>(
            yln_h, embed, nullptr, out, T_TOK, VOCAB, HIDDEN);
}